// Round 1
// baseline (538.386 us; speedup 1.0000x reference)
//
#include <hip/hip_runtime.h>

// Subtractor50Bit: A - B via two's complement, N rows x 50 bits ({0,1} floats).
// out = [result (N*50 floats), borrow (N floats)].
//
// Strategy: each wave handles 64 rows = 3200 contiguous elements.
//  - Coalesced dword loads + __ballot pack 64 elements/instr into bit-words.
//  - Each lane reconstructs its row's 50-bit integer from <=2 ballot words.
//  - 64-bit integer subtract gives sum bits and borrow directly.
//  - Coalesced stores via __shfl of the owning row's diff word.

constexpr int BITS = 50;
constexpr unsigned long long MASK50 = (1ULL << BITS) - 1ULL;

__device__ inline unsigned long long shfl64(unsigned long long v, int src) {
    int lo = __shfl((int)(unsigned)(v & 0xffffffffULL), src, 64);
    int hi = __shfl((int)(unsigned)(v >> 32), src, 64);
    return ((unsigned long long)(unsigned)hi << 32) | (unsigned long long)(unsigned)lo;
}

__global__ __launch_bounds__(256) void Subtractor50Bit_kernel(
    const float* __restrict__ A, const float* __restrict__ B,
    float* __restrict__ out, int N)
{
    const int lane = threadIdx.x & 63;
    const int wv   = threadIdx.x >> 6;
    const long long waveIdx = (long long)blockIdx.x * 4 + wv;
    const long long rowBase = waveIdx * 64;
    if (rowBase >= N) return;

    if (rowBase + 64 <= N) {
        // ---- full-wave fast path (all 64 lanes active) ----
        const long long eBase = rowBase * BITS;   // 3200 elements per wave
        const int p0   = BITS * lane;             // first bit position of my row
        const int idx0 = p0 >> 6;                 // ballot word holding bit p0
        const int sh   = p0 & 63;

        unsigned long long a0 = 0, a1 = 0, b0 = 0, b1 = 0;
        #pragma unroll
        for (int j = 0; j < BITS; ++j) {
            float va = A[eBase + j * 64 + lane];          // coalesced 256B/instr
            unsigned long long m = __ballot(va != 0.0f);  // 64 bits packed
            if (j == idx0)     a0 = m;
            if (j == idx0 + 1) a1 = m;
        }
        #pragma unroll
        for (int j = 0; j < BITS; ++j) {
            float vb = B[eBase + j * 64 + lane];
            unsigned long long m = __ballot(vb != 0.0f);
            if (j == idx0)     b0 = m;
            if (j == idx0 + 1) b1 = m;
        }

        unsigned long long av = a0 >> sh;
        unsigned long long bv = b0 >> sh;
        if (sh > 64 - BITS) {       // need bits from the next word
            av |= a1 << (64 - sh);
            bv |= b1 << (64 - sh);
        }
        av &= MASK50;
        bv &= MASK50;

        unsigned long long diff = (av - bv) & MASK50; // = sum bits of A + ~B + 1
        float borrow = (av < bv) ? 1.0f : 0.0f;       // = 1 - carry_out

        // ---- coalesced result store: lane writes flat element j*64+lane ----
        #pragma unroll
        for (int j = 0; j < BITS; ++j) {
            int local = j * 64 + lane;      // [0, 3200)
            int r     = local / BITS;       // owning local row (magic-mul)
            int bit   = local - r * BITS;   // bit index within that row
            unsigned long long dr = shfl64(diff, r);  // only 2 distinct srcs/iter
            out[eBase + local] = (float)((dr >> bit) & 1ULL);
        }
        // borrow segment: naturally coalesced
        out[(long long)N * BITS + rowBase + lane] = borrow;
    } else {
        // ---- scalar tail path (partial wave; N%64!=0 safety net) ----
        long long r = rowBase + lane;
        if (r < N) {
            unsigned long long av = 0, bv = 0;
            for (int k = 0; k < BITS; ++k) {
                av |= (unsigned long long)(A[r * BITS + k] != 0.0f) << k;
                bv |= (unsigned long long)(B[r * BITS + k] != 0.0f) << k;
            }
            unsigned long long diff = (av - bv) & MASK50;
            for (int k = 0; k < BITS; ++k)
                out[r * BITS + k] = (float)((diff >> k) & 1ULL);
            out[(long long)N * BITS + r] = (av < bv) ? 1.0f : 0.0f;
        }
    }
}

extern "C" void kernel_launch(void* const* d_in, const int* in_sizes, int n_in,
                              void* d_out, int out_size, void* d_ws, size_t ws_size,
                              hipStream_t stream) {
    const float* A = (const float*)d_in[0];
    const float* B = (const float*)d_in[1];
    float* out = (float*)d_out;
    const int N = in_sizes[0] / BITS;          // 1,000,000

    const int waves  = (N + 63) / 64;          // one wave per 64 rows
    const int blocks = (waves + 3) / 4;        // 4 waves per 256-thread block
    Subtractor50Bit_kernel<<<blocks, 256, 0, stream>>>(A, B, out, N);
}

// Round 2
// 447.572 us; speedup vs baseline: 1.2029x; 1.2029x over previous
//
#include <hip/hip_runtime.h>

// Subtractor50Bit: A - B via two's complement, N rows x 50 bits ({0,1} floats).
// out = [result (N*50 floats), borrow (N floats)].
//
// R1: latency-bound fix. Phase-split loads (explicit fa[50]/fb[50] register
// arrays -> ~50-100 loads in flight per wave) from the convergent __ballot
// phase; capture ballot word j into lane j (cheap) and distribute with 4
// shfl64s. Store phase identical to the R0 passing version.

constexpr int BITS = 50;
constexpr unsigned long long MASK50 = (1ULL << BITS) - 1ULL;

__device__ inline unsigned long long shfl64(unsigned long long v, int src) {
    int lo = __shfl((int)(unsigned)(v & 0xffffffffULL), src, 64);
    int hi = __shfl((int)(unsigned)(v >> 32), src, 64);
    return ((unsigned long long)(unsigned)hi << 32) | (unsigned long long)(unsigned)lo;
}

__global__ __launch_bounds__(256) void Subtractor50Bit_kernel(
    const float* __restrict__ A, const float* __restrict__ B,
    float* __restrict__ out, int N)
{
    const int lane = threadIdx.x & 63;
    const int wv   = threadIdx.x >> 6;
    const long long waveIdx = (long long)blockIdx.x * 4 + wv;
    const long long rowBase = waveIdx * 64;
    if (rowBase >= N) return;

    if (rowBase + 64 <= N) {
        // ---- full-wave fast path (all 64 lanes active) ----
        const long long eBase = rowBase * BITS;   // 3200 elements per wave
        const float* pa = A + eBase + lane;
        const float* pb = B + eBase + lane;

        // Phase 1: issue ALL loads first (independent, coalesced 256B/instr).
        // No convergent ops in between -> compiler keeps them in flight.
        float fa[BITS], fb[BITS];
        #pragma unroll
        for (int j = 0; j < BITS; ++j) fa[j] = pa[(long long)j * 64];
        #pragma unroll
        for (int j = 0; j < BITS; ++j) fb[j] = pb[(long long)j * 64];

        // Phase 2: ballots; lane j keeps word j (single cmp + cndmask pair).
        unsigned long long wa = 0, wb = 0;
        #pragma unroll
        for (int j = 0; j < BITS; ++j) {
            unsigned long long ma = __ballot(fa[j] != 0.0f);
            unsigned long long mb = __ballot(fb[j] != 0.0f);
            if (lane == j) { wa = ma; wb = mb; }
        }

        // Phase 3: distribute — lane needs ballot words idx0, idx0+1.
        const int p0   = BITS * lane;
        const int idx0 = p0 >> 6;
        const int sh   = p0 & 63;
        unsigned long long a0 = shfl64(wa, idx0);
        unsigned long long a1 = shfl64(wa, idx0 + 1);   // lane 50 -> 0, unused when sh<=14
        unsigned long long b0 = shfl64(wb, idx0);
        unsigned long long b1 = shfl64(wb, idx0 + 1);

        unsigned long long av = a0 >> sh;
        unsigned long long bv = b0 >> sh;
        if (sh > 64 - BITS) {       // need bits from the next word
            av |= a1 << (64 - sh);
            bv |= b1 << (64 - sh);
        }
        av &= MASK50;
        bv &= MASK50;

        unsigned long long diff = (av - bv) & MASK50; // = sum bits of A + ~B + 1
        float borrow = (av < bv) ? 1.0f : 0.0f;       // = 1 - carry_out

        // ---- coalesced result store: lane writes flat element j*64+lane ----
        #pragma unroll
        for (int j = 0; j < BITS; ++j) {
            int local = j * 64 + lane;      // [0, 3200)
            int r     = local / BITS;       // owning local row (magic-mul)
            int bit   = local - r * BITS;   // bit index within that row
            unsigned long long dr = shfl64(diff, r);  // only 2-3 distinct srcs/iter
            out[eBase + local] = (float)((dr >> bit) & 1ULL);
        }
        // borrow segment: naturally coalesced
        out[(long long)N * BITS + rowBase + lane] = borrow;
    } else {
        // ---- scalar tail path (partial wave; N%64!=0 safety net) ----
        long long r = rowBase + lane;
        if (r < N) {
            unsigned long long av = 0, bv = 0;
            for (int k = 0; k < BITS; ++k) {
                av |= (unsigned long long)(A[r * BITS + k] != 0.0f) << k;
                bv |= (unsigned long long)(B[r * BITS + k] != 0.0f) << k;
            }
            unsigned long long diff = (av - bv) & MASK50;
            for (int k = 0; k < BITS; ++k)
                out[r * BITS + k] = (float)((diff >> k) & 1ULL);
            out[(long long)N * BITS + r] = (av < bv) ? 1.0f : 0.0f;
        }
    }
}

extern "C" void kernel_launch(void* const* d_in, const int* in_sizes, int n_in,
                              void* d_out, int out_size, void* d_ws, size_t ws_size,
                              hipStream_t stream) {
    const float* A = (const float*)d_in[0];
    const float* B = (const float*)d_in[1];
    float* out = (float*)d_out;
    const int N = in_sizes[0] / BITS;          // 1,000,000

    const int waves  = (N + 63) / 64;          // one wave per 64 rows
    const int blocks = (waves + 3) / 4;        // 4 waves per 256-thread block
    Subtractor50Bit_kernel<<<blocks, 256, 0, stream>>>(A, B, out, N);
}